// Round 9
// baseline (359.932 us; speedup 1.0000x reference)
//
#include <hip/hip_runtime.h>
#include <cmath>

typedef float f4 __attribute__((ext_vector_type(4)));

#define SCALEF 8.0f   // alpha/rank = 32/4
#define NBLK   4096   // blocks; each handles 2 groups x 2 tokens = 4 tokens

// Raw barrier: LDS visibility only (lgkmcnt), does NOT drain vmcnt ->
// global prefetches stay in flight across it (unlike __syncthreads()).
#define LDS_BARRIER()                                        \
    asm volatile("s_waitcnt lgkmcnt(0)" ::: "memory");       \
    __builtin_amdgcn_s_barrier();                            \
    asm volatile("" ::: "memory")

__global__ __launch_bounds__(256, 4) void tmlora(
    const float* __restrict__ x,
    const float* __restrict__ A_w,
    const float* __restrict__ B_w,
    const float* __restrict__ router_w,
    const float* __restrict__ expert_vectors,
    float* __restrict__ out)
{
    const int tid  = threadIdx.x;
    const int b    = blockIdx.x;
    const int wid  = tid >> 6, lane = tid & 63;

    const f4* __restrict__ x4 = (const f4*)x;        // [ntok][1024]
    const f4* __restrict__ r4 = (const f4*)router_w; // [8][1024]
    const f4* __restrict__ a4 = (const f4*)A_w;      // [4][1024]
    const f4* __restrict__ b4 = (const f4*)B_w;      // [4096] rows (1 f4 each)

    __shared__ float red[2][4][24];   // [group][wave][2 tok x 12]

#define ROWPTR(W) ((W) < 8 ? (r4 + (size_t)(W) * 1024) : (a4 + (size_t)((W) - 8) * 1024))

    f4 xv0[8], xv1[8];     // disjoint live ranges; allocator overlays them
    f4 wbuf[2][4];         // 2-slot ping-pong, 1 row lookahead
    float acc[2][12];
    float h[2][4];

    const int t0 = b * 2;          // group 0 tokens
    const int t1 = 8192 + b * 2;   // group 1 tokens

    // ================= prologue: group-0 x + weight row 0 =================
#pragma unroll
    for (int p = 0; p < 4; ++p)
#pragma unroll
        for (int tk = 0; tk < 2; ++tk)
            xv0[tk * 4 + p] = x4[(size_t)(t0 + tk) * 1024 + p * 256 + tid];
#pragma unroll
    for (int p = 0; p < 4; ++p) wbuf[0][p] = ROWPTR(0)[p * 256 + tid];

    // =========================== GROUP macro ==============================
    // XV: x regs for this group; RED: red buffer idx; TOK0: first token;
    // POSTFMA: code emitted right after the FMA phase (prefetch window).
#define GROUP(XV, RED, TOK0, POSTFMA)                                          \
  {                                                                            \
    _Pragma("unroll")                                                          \
    for (int tk = 0; tk < 2; ++tk)                                             \
      _Pragma("unroll")                                                        \
      for (int w = 0; w < 12; ++w) acc[tk][w] = 0.f;                           \
    _Pragma("unroll")                                                          \
    for (int w = 0; w < 12; ++w) {                                             \
      if (w + 1 < 12) {                                                        \
        const f4* __restrict__ rp = ROWPTR(w + 1);                             \
        _Pragma("unroll")                                                      \
        for (int p = 0; p < 4; ++p)                                            \
          wbuf[(w + 1) & 1][p] = rp[p * 256 + tid];                            \
      }                                                                        \
      _Pragma("unroll")                                                        \
      for (int p = 0; p < 4; ++p) {                                            \
        const f4 wv = wbuf[w & 1][p];                                          \
        _Pragma("unroll")                                                      \
        for (int tk = 0; tk < 2; ++tk) {                                       \
          acc[tk][w] = fmaf(XV[tk * 4 + p][0], wv[0], acc[tk][w]);             \
          acc[tk][w] = fmaf(XV[tk * 4 + p][1], wv[1], acc[tk][w]);             \
          acc[tk][w] = fmaf(XV[tk * 4 + p][2], wv[2], acc[tk][w]);             \
          acc[tk][w] = fmaf(XV[tk * 4 + p][3], wv[3], acc[tk][w]);             \
        }                                                                      \
      }                                                                        \
    }                                                                          \
    POSTFMA                                                                    \
    /* wave butterfly (24 values) */                                           \
    _Pragma("unroll")                                                          \
    for (int tk = 0; tk < 2; ++tk)                                             \
      _Pragma("unroll")                                                        \
      for (int w = 0; w < 12; ++w) {                                           \
        float v = acc[tk][w];                                                  \
        _Pragma("unroll")                                                      \
        for (int m = 1; m < 64; m <<= 1) v += __shfl_xor(v, m, 64);            \
        acc[tk][w] = v;                                                        \
      }                                                                        \
    if (lane == 0) {                                                           \
      _Pragma("unroll")                                                        \
      for (int tk = 0; tk < 2; ++tk)                                           \
        _Pragma("unroll")                                                      \
        for (int w = 0; w < 12; ++w) red[RED][wid][tk * 12 + w] = acc[tk][w];  \
    }                                                                          \
    LDS_BARRIER();   /* vmcnt NOT drained: prefetches keep flying */           \
    /* all-lane cross-wave sum (broadcast f4 LDS reads) */                     \
    {                                                                          \
      const f4* __restrict__ rr = (const f4*)&red[RED][0][0];                  \
      _Pragma("unroll")                                                        \
      for (int tk = 0; tk < 2; ++tk)                                           \
        _Pragma("unroll")                                                      \
        for (int k = 0; k < 3; ++k) {                                          \
          const f4 s = rr[0 * 6 + tk * 3 + k] + rr[1 * 6 + tk * 3 + k] +       \
                       rr[2 * 6 + tk * 3 + k] + rr[3 * 6 + tk * 3 + k];        \
          acc[tk][4 * k + 0] = s[0];                                           \
          acc[tk][4 * k + 1] = s[1];                                           \
          acc[tk][4 * k + 2] = s[2];                                           \
          acc[tk][4 * k + 3] = s[3];                                           \
        }                                                                      \
    }                                                                          \
    /* all-lane epilogue: top-4 / softmax / expert mix / exact gelu */         \
    _Pragma("unroll")                                                          \
    for (int tk = 0; tk < 2; ++tk) {                                           \
      int   idx[4];                                                            \
      float val[4];                                                            \
      _Pragma("unroll")                                                        \
      for (int k = 0; k < 4; ++k) {                                            \
        int bi = 0; float bv = acc[tk][0];                                     \
        _Pragma("unroll")                                                      \
        for (int e = 1; e < 8; ++e)                                            \
          if (acc[tk][e] > bv) { bv = acc[tk][e]; bi = e; }                    \
        idx[k] = bi; val[k] = bv;                                              \
        _Pragma("unroll")                                                      \
        for (int e = 0; e < 8; ++e)                                            \
          if (e == bi) acc[tk][e] = -INFINITY;                                 \
      }                                                                        \
      float ex[4], se = 0.f;                                                   \
      _Pragma("unroll")                                                        \
      for (int k = 0; k < 4; ++k) { ex[k] = expf(val[k] - val[0]); se += ex[k]; } \
      const float inv = 1.f / se;                                              \
      float Et[4] = {0.f, 0.f, 0.f, 0.f};                                      \
      _Pragma("unroll")                                                        \
      for (int k = 0; k < 4; ++k) {                                            \
        const float wgt = ex[k] * inv;                                         \
        _Pragma("unroll")                                                      \
        for (int r = 0; r < 4; ++r)                                            \
          Et[r] = fmaf(wgt, expert_vectors[idx[k] * 4 + r], Et[r]);            \
      }                                                                        \
      _Pragma("unroll")                                                        \
      for (int r = 0; r < 4; ++r) {                                            \
        const float hv = acc[tk][8 + r] + Et[r];                               \
        h[tk][r] = SCALEF * 0.5f * hv *                                        \
                   (1.f + erff(hv * 0.70710678118654752f));                    \
      }                                                                        \
    }                                                                          \
    /* store phase: B_w from L2 per-j, 8 nt stores */                          \
    _Pragma("unroll")                                                          \
    for (int j = 0; j < 4; ++j) {                                              \
      const int c = tid + 256 * j;                                             \
      const f4 B0 = b4[4 * c + 0], B1 = b4[4 * c + 1],                         \
               B2 = b4[4 * c + 2], B3 = b4[4 * c + 3];                         \
      _Pragma("unroll")                                                        \
      for (int tk = 0; tk < 2; ++tk) {                                         \
        const float h0 = h[tk][0], h1 = h[tk][1],                              \
                    h2 = h[tk][2], h3 = h[tk][3];                              \
        f4 v;                                                                  \
        v[0] = B0[0] * h0 + B0[1] * h1 + B0[2] * h2 + B0[3] * h3;              \
        v[1] = B1[0] * h0 + B1[1] * h1 + B1[2] * h2 + B1[3] * h3;              \
        v[2] = B2[0] * h0 + B2[1] * h1 + B2[2] * h2 + B2[3] * h3;              \
        v[3] = B3[0] * h0 + B3[1] * h1 + B3[2] * h2 + B3[3] * h3;              \
        __builtin_nontemporal_store(                                           \
            v, (f4*)out + (size_t)((TOK0) + tk) * 1024 + c);                   \
      }                                                                        \
    }                                                                          \
  }

    // ---- group 0: after its FMA, prefetch group-1 x + weight row 0 ----
    GROUP(xv0, 0, t0,
        _Pragma("unroll")
        for (int p = 0; p < 4; ++p)
            _Pragma("unroll")
            for (int tk = 0; tk < 2; ++tk)
                xv1[tk * 4 + p] = x4[(size_t)(t1 + tk) * 1024 + p * 256 + tid];
        _Pragma("unroll")
        for (int p = 0; p < 4; ++p) wbuf[0][p] = ROWPTR(0)[p * 256 + tid];
    )

    // ---- group 1: no further prefetch ----
    GROUP(xv1, 1, t1, )

#undef GROUP
#undef ROWPTR
}

extern "C" void kernel_launch(void* const* d_in, const int* in_sizes, int n_in,
                              void* d_out, int out_size, void* d_ws, size_t ws_size,
                              hipStream_t stream) {
    const float* x        = (const float*)d_in[0];
    const float* A_w      = (const float*)d_in[1];
    const float* B_w      = (const float*)d_in[2];
    const float* router_w = (const float*)d_in[3];
    const float* ev       = (const float*)d_in[4];
    float* out            = (float*)d_out;

    tmlora<<<NBLK, 256, 0, stream>>>(x, A_w, B_w, router_w, ev, out);
}

// Round 10
// 205.735 us; speedup vs baseline: 1.7495x; 1.7495x over previous
//
#include <hip/hip_runtime.h>
#include <cmath>
#include <stdint.h>

typedef float f4 __attribute__((ext_vector_type(4)));
typedef unsigned short u16x8 __attribute__((ext_vector_type(8)));

#define SCALEF 8.0f   // alpha/rank = 32/4

// ---------------- k0: pack 12 weight rows f32 -> bf16, interleaved ---------
// wq[w][c][0..3] = bf16(W[w][4c..4c+3]); [4..7] = bf16(W[w][2048+4c..2048+4c+3])
__global__ __launch_bounds__(256, 4) void k0_pack(
    const float* __restrict__ A_w,
    const float* __restrict__ router_w,
    unsigned short* __restrict__ wq)
{
    const int idx = blockIdx.x * 256 + threadIdx.x;   // 0..6143
    if (idx >= 12 * 512) return;
    const int w = idx >> 9, c = idx & 511;
    const float* __restrict__ row = (w < 8) ? (router_w + (size_t)w * 4096)
                                            : (A_w + (size_t)(w - 8) * 4096);
    u16x8 o;
#pragma unroll
    for (int j = 0; j < 4; ++j) {
        union { float f; unsigned u; } a, b;
        a.f = row[4 * c + j];
        b.f = row[2048 + 4 * c + j];
        o[j]     = (unsigned short)((a.u + 0x7FFFu + ((a.u >> 16) & 1u)) >> 16);
        o[4 + j] = (unsigned short)((b.u + 0x7FFFu + ((b.u >> 16) & 1u)) >> 16);
    }
    *(u16x8*)(wq + (size_t)idx * 8) = o;
}

// ---- async global->LDS, 16B per lane; LDS dest wave-uniform ----
typedef __attribute__((address_space(3))) unsigned int  lds_u32;
typedef __attribute__((address_space(1))) const unsigned int glb_u32;
__device__ __forceinline__ void stage16(const void* g, void* l) {
    __builtin_amdgcn_global_load_lds((glb_u32*)g, (lds_u32*)l, 16, 0, 0);
}

#define LDS_BAR() do { asm volatile("s_waitcnt lgkmcnt(0)" ::: "memory"); \
                       __builtin_amdgcn_s_barrier(); } while (0)

// ---------------- main: 256 blocks x 512 thr, 64 tokens/block --------------
__global__ __launch_bounds__(512, 1) void tmlora_main(
    const float* __restrict__ x,
    const unsigned short* __restrict__ wq,
    const float* __restrict__ B_w,
    const float* __restrict__ expert_vectors,
    float* __restrict__ out)
{
    __shared__ __align__(16) unsigned short wlds[12 * 512 * 8];  // 96 KB bf16 weights
    __shared__ __align__(16) float xlds[3][4096];                // 48 KB x triple-buf
    __shared__ __align__(16) float red[8][8][12];                // [tokslot][wave][12]
    __shared__ __align__(16) f4    hsh[8];                       // h per batch token
    __shared__ __align__(16) float evl[32];                      // expert_vectors

    const int tid  = threadIdx.x;        // 0..511
    const int wid  = tid >> 6;           // 0..7
    const int lane = tid & 63;
    const int tok0 = blockIdx.x * 64;

    // ---- prologue: B chunks -> regs (oldest vm ops, drained at first wait) ----
    const f4* __restrict__ b4 = (const f4*)B_w;
    f4 Bc[2][4];
#pragma unroll
    for (int m = 0; m < 4; ++m) Bc[0][m] = b4[4 * tid + m];
#pragma unroll
    for (int m = 0; m < 4; ++m) Bc[1][m] = b4[4 * (tid + 512) + m];
    if (tid < 8) {
        const f4 e = ((const f4*)expert_vectors)[tid];
        *(f4*)&evl[tid * 4] = e;
    }

    // ---- stage weights (12 x 1KB per wave) + x tokens 0,1 ----
#pragma unroll
    for (int j = 0; j < 12; ++j) {
        const int off = wid * 12288 + j * 1024;
        stage16((const char*)wq + off + lane * 16, (char*)wlds + off);
    }
#pragma unroll
    for (int t = 0; t < 2; ++t) {
        const char* src = (const char*)(x + (size_t)(tok0 + t) * 4096);
#pragma unroll
        for (int i = 0; i < 2; ++i) {
            const int off = wid * 2048 + i * 1024;
            stage16(src + off + lane * 16, (char*)&xlds[t][0] + off);
        }
    }

#pragma unroll 1
    for (int t = 0; t < 64; ++t) {
        // ---- wait for stage(t); stage(t+1) stays in flight ----
        if (t < 63) asm volatile("s_waitcnt vmcnt(2) lgkmcnt(0)" ::: "memory");
        else        asm volatile("s_waitcnt vmcnt(0) lgkmcnt(0)" ::: "memory");
        __builtin_amdgcn_s_barrier();
        __builtin_amdgcn_sched_barrier(0);

        // ---- issue stage(t+2) immediately (flies under FMA/epilogue) ----
        if (t + 2 < 64) {
            const char* src = (const char*)(x + (size_t)(tok0 + t + 2) * 4096);
            char* dst = (char*)&xlds[(t + 2) % 3][0];
#pragma unroll
            for (int i = 0; i < 2; ++i) {
                const int off = wid * 2048 + i * 1024;
                stage16(src + off + lane * 16, dst + off);
            }
        }
        __builtin_amdgcn_sched_barrier(0);

        // ---- FMA: 12 dots, thread covers cols [4t..4t+4) and [2048+4t..) ----
        const float* __restrict__ xb = &xlds[t % 3][0];
        const f4 xa = *(const f4*)(xb + 4 * tid);
        const f4 xc = *(const f4*)(xb + 2048 + 4 * tid);

        float acc[12];
        const u16x8* __restrict__ wrow = (const u16x8*)wlds + tid;
#pragma unroll
        for (int w = 0; w < 12; ++w) {
            const u16x8 wv = wrow[w * 512];
            const unsigned* dv = (const unsigned*)&wv;
            const float f0 = __uint_as_float(dv[0] << 16);
            const float f1 = __uint_as_float(dv[0] & 0xFFFF0000u);
            const float f2 = __uint_as_float(dv[1] << 16);
            const float f3 = __uint_as_float(dv[1] & 0xFFFF0000u);
            const float g0 = __uint_as_float(dv[2] << 16);
            const float g1 = __uint_as_float(dv[2] & 0xFFFF0000u);
            const float g2 = __uint_as_float(dv[3] << 16);
            const float g3 = __uint_as_float(dv[3] & 0xFFFF0000u);
            float s = xa[0] * f0;
            s = fmaf(xa[1], f1, s);
            s = fmaf(xa[2], f2, s);
            s = fmaf(xa[3], f3, s);
            s = fmaf(xc[0], g0, s);
            s = fmaf(xc[1], g1, s);
            s = fmaf(xc[2], g2, s);
            s = fmaf(xc[3], g3, s);
            acc[w] = s;
        }

        // ---- wave butterfly ----
#pragma unroll
        for (int w = 0; w < 12; ++w) {
            float v = acc[w];
#pragma unroll
            for (int m = 1; m < 64; m <<= 1) v += __shfl_xor(v, m, 64);
            acc[w] = v;
        }
        if (lane == 0) {
            f4* rw = (f4*)&red[t & 7][wid][0];
            rw[0] = (f4){acc[0], acc[1], acc[2],  acc[3]};
            rw[1] = (f4){acc[4], acc[5], acc[6],  acc[7]};
            rw[2] = (f4){acc[8], acc[9], acc[10], acc[11]};
        }

        // ---- every 8 tokens: batched epilogue (1 token per wave) + stores ----
        if ((t & 7) == 7) {
            LDS_BAR();   // red visible

            float s12[12];
            {
                const f4* rp = (const f4*)&red[wid][0][0];   // my token's slot
                f4 a0 = rp[0], a1 = rp[1], a2 = rp[2];
#pragma unroll
                for (int j = 1; j < 8; ++j) {
                    a0 += rp[j * 3 + 0];
                    a1 += rp[j * 3 + 1];
                    a2 += rp[j * 3 + 2];
                }
#pragma unroll
                for (int k = 0; k < 4; ++k) {
                    s12[k] = a0[k]; s12[4 + k] = a1[k]; s12[8 + k] = a2[k];
                }
            }
            // top-4 (first-index ties) / softmax / expert mix / exact gelu
            int   idx[4];
            float val[4];
#pragma unroll
            for (int k = 0; k < 4; ++k) {
                int bi = 0; float bv = s12[0];
#pragma unroll
                for (int e = 1; e < 8; ++e)
                    if (s12[e] > bv) { bv = s12[e]; bi = e; }
                idx[k] = bi; val[k] = bv;
#pragma unroll
                for (int e = 0; e < 8; ++e)
                    if (e == bi) s12[e] = -INFINITY;   // static-index knockout
            }
            float ex[4], se = 0.f;
#pragma unroll
            for (int k = 0; k < 4; ++k) { ex[k] = expf(val[k] - val[0]); se += ex[k]; }
            const float inv = 1.f / se;
            float Et[4] = {0.f, 0.f, 0.f, 0.f};
#pragma unroll
            for (int k = 0; k < 4; ++k) {
                const float wgt = ex[k] * inv;
#pragma unroll
                for (int r = 0; r < 4; ++r)
                    Et[r] = fmaf(wgt, evl[idx[k] * 4 + r], Et[r]);
            }
            f4 hv4;
#pragma unroll
            for (int r = 0; r < 4; ++r) {
                const float hv = s12[8 + r] + Et[r];
                hv4[r] = SCALEF * 0.5f * hv *
                         (1.f + erff(hv * 0.70710678118654752f));
            }
            if (lane == 0) hsh[wid] = hv4;
            LDS_BAR();   // hsh visible

            // stores: 8 tokens x 2 chunks/thread, B from regs, nt stores
            const int tb0 = tok0 + (t - 7);
#pragma unroll
            for (int tk = 0; tk < 8; ++tk) {
                const f4 hh = hsh[tk];
#pragma unroll
                for (int cc = 0; cc < 2; ++cc) {
                    const int c = tid + cc * 512;
                    f4 v;
                    v[0] = Bc[cc][0][0]*hh[0] + Bc[cc][0][1]*hh[1] + Bc[cc][0][2]*hh[2] + Bc[cc][0][3]*hh[3];
                    v[1] = Bc[cc][1][0]*hh[0] + Bc[cc][1][1]*hh[1] + Bc[cc][1][2]*hh[2] + Bc[cc][1][3]*hh[3];
                    v[2] = Bc[cc][2][0]*hh[0] + Bc[cc][2][1]*hh[1] + Bc[cc][2][2]*hh[2] + Bc[cc][2][3]*hh[3];
                    v[3] = Bc[cc][3][0]*hh[0] + Bc[cc][3][1]*hh[1] + Bc[cc][3][2]*hh[2] + Bc[cc][3][3]*hh[3];
                    __builtin_nontemporal_store(
                        v, (f4*)out + (size_t)(tb0 + tk) * 1024 + c);
                }
            }
        }
    }
}

extern "C" void kernel_launch(void* const* d_in, const int* in_sizes, int n_in,
                              void* d_out, int out_size, void* d_ws, size_t ws_size,
                              hipStream_t stream) {
    const float* x        = (const float*)d_in[0];
    const float* A_w      = (const float*)d_in[1];
    const float* B_w      = (const float*)d_in[2];
    const float* router_w = (const float*)d_in[3];
    const float* ev       = (const float*)d_in[4];
    float* out            = (float*)d_out;
    unsigned short* wq    = (unsigned short*)d_ws;   // 96 KB bf16 weights

    k0_pack<<<24, 256, 0, stream>>>(A_w, router_w, wq);
    tmlora_main<<<256, 512, 0, stream>>>(x, wq, B_w, ev, out);
}

// Round 11
// 106.138 us; speedup vs baseline: 3.3912x; 1.9384x over previous
//
#include <hip/hip_runtime.h>
#include <cmath>

typedef float f4 __attribute__((ext_vector_type(4)));
typedef float f32x4 __attribute__((ext_vector_type(4)));
typedef short bf16x8 __attribute__((ext_vector_type(8)));
typedef unsigned short u16x8 __attribute__((ext_vector_type(8)));
typedef unsigned int u32x4 __attribute__((ext_vector_type(4)));

#define SCALEF 8.0f   // alpha/rank = 32/4

__device__ __forceinline__ unsigned cvtpk(float lo, float hi) {
    unsigned r;
    asm("v_cvt_pk_bf16_f32 %0, %1, %2" : "=v"(r) : "v"(lo), "v"(hi));
    return r;
}

// 8 consecutive-k f32 -> bf16x8 A-fragment (elem j = k j)
__device__ __forceinline__ bf16x8 packA(const f4 a, const f4 b) {
    u32x4 u;
    u[0] = cvtpk(a[0], a[1]);
    u[1] = cvtpk(a[2], a[3]);
    u[2] = cvtpk(b[0], b[1]);
    u[3] = cvtpk(b[2], b[3]);
    return __builtin_bit_cast(bf16x8, u);
}

// ---- k0: prepack 12 weight rows into MFMA B-fragment stream (bf16) -------
// entry idx = s*64 + l (s = k-step 0..127, l = lane): 8 bf16 =
// W[l&15][32s + (l>>4)*8 + j], zero-padded for w >= 12.  128 KB total.
__global__ __launch_bounds__(256, 4) void k0_pack(
    const float* __restrict__ A_w,
    const float* __restrict__ router_w,
    unsigned short* __restrict__ wq)
{
    const int idx = blockIdx.x * 256 + threadIdx.x;   // 0..8191
    const int l = idx & 63, s = idx >> 6;
    const int w = l & 15;
    const int kb = 32 * s + (l >> 4) * 8;
    u16x8 o = (u16x8)0;
    if (w < 12) {
        const float* __restrict__ row = (w < 8)
            ? router_w + (size_t)w * 4096
            : A_w + (size_t)(w - 8) * 4096;
#pragma unroll
        for (int j = 0; j < 8; ++j) {
            union { float f; unsigned u; } a;
            a.f = row[kb + j];
            o[j] = (unsigned short)((a.u + 0x7FFFu + ((a.u >> 16) & 1u)) >> 16);
        }
    }
    *((u16x8*)wq + idx) = o;
}

// ---- main: 256 blocks x 4 waves; each wave = one 16-token tile, no bars ---
__global__ __launch_bounds__(256, 1) void tmlora_main(
    const float* __restrict__ x,
    const unsigned short* __restrict__ wq,
    const float* __restrict__ B_w,
    const float* __restrict__ expert_vectors,
    float* __restrict__ out)
{
    __shared__ float csh[4][16][17];   // per-wave C transpose, pad->conflict-free
    __shared__ f4    hsh[4][16];       // per-wave h

    const int tid  = threadIdx.x;
    const int wid  = tid >> 6, lane = tid & 63;
    const int tok0 = (blockIdx.x * 4 + wid) * 16;

    // A: lane l covers row tok0+(l&15), k-chunk (l>>4)*8 within each step
    const f4* __restrict__ xr =
        (const f4*)x + ((size_t)(tok0 + (lane & 15)) << 10) + ((lane >> 4) << 1);
    const u16x8* __restrict__ wr = (const u16x8*)wq + lane;

    // ---- K-loop: 128 steps, two banks of 4, ~8 steps of loads in flight ----
    f4 a0[4], a1[4], c0[4], c1[4];
    u16x8 wb[4], wc[4];
#pragma unroll
    for (int i = 0; i < 4; ++i) {
        a0[i] = xr[8 * i];
        a1[i] = xr[8 * i + 1];
        wb[i] = wr[i << 6];
    }
#pragma unroll
    for (int i = 0; i < 4; ++i) {
        c0[i] = xr[8 * (4 + i)];
        c1[i] = xr[8 * (4 + i) + 1];
        wc[i] = wr[(4 + i) << 6];
    }

    f32x4 acc = {0.f, 0.f, 0.f, 0.f};

#pragma unroll 1
    for (int it = 0; it < 16; ++it) {
        const int sb = it * 8;
#pragma unroll
        for (int i = 0; i < 4; ++i)
            acc = __builtin_amdgcn_mfma_f32_16x16x32_bf16(
                packA(a0[i], a1[i]), __builtin_bit_cast(bf16x8, wb[i]), acc, 0, 0, 0);
        if (it < 15) {
#pragma unroll
            for (int i = 0; i < 4; ++i) {
                a0[i] = xr[8 * (sb + 8 + i)];
                a1[i] = xr[8 * (sb + 8 + i) + 1];
                wb[i] = wr[(sb + 8 + i) << 6];
            }
        }
#pragma unroll
        for (int i = 0; i < 4; ++i)
            acc = __builtin_amdgcn_mfma_f32_16x16x32_bf16(
                packA(c0[i], c1[i]), __builtin_bit_cast(bf16x8, wc[i]), acc, 0, 0, 0);
        if (it < 15) {
#pragma unroll
            for (int i = 0; i < 4; ++i) {
                c0[i] = xr[8 * (sb + 12 + i)];
                c1[i] = xr[8 * (sb + 12 + i) + 1];
                wc[i] = wr[(sb + 12 + i) << 6];
            }
        }
    }

    // ---- C -> LDS transpose (wave-private; lgkmcnt only, no barrier) ----
    // lane holds scores[token=(lane>>4)*4+r][weight=lane&15]
#pragma unroll
    for (int r = 0; r < 4; ++r)
        csh[wid][(lane >> 4) * 4 + r][lane & 15] = acc[r];
    asm volatile("s_waitcnt lgkmcnt(0)" ::: "memory");

    // ---- epilogue: lanes 0..15, one token each ----
    if (lane < 16) {
        float s12[12];
#pragma unroll
        for (int w = 0; w < 12; ++w) s12[w] = csh[wid][lane][w];

        int   idx[4];
        float val[4];
#pragma unroll
        for (int k = 0; k < 4; ++k) {
            int bi = 0; float bv = s12[0];
#pragma unroll
            for (int e = 1; e < 8; ++e)
                if (s12[e] > bv) { bv = s12[e]; bi = e; }
            idx[k] = bi; val[k] = bv;
#pragma unroll
            for (int e = 0; e < 8; ++e)
                if (e == bi) s12[e] = -INFINITY;   // static-index knockout
        }
        float ex[4], se = 0.f;
#pragma unroll
        for (int k = 0; k < 4; ++k) { ex[k] = expf(val[k] - val[0]); se += ex[k]; }
        const float inv = 1.f / se;
        float Et[4] = {0.f, 0.f, 0.f, 0.f};
#pragma unroll
        for (int k = 0; k < 4; ++k) {
            const float wgt = ex[k] * inv;
#pragma unroll
            for (int r = 0; r < 4; ++r)
                Et[r] = fmaf(wgt, expert_vectors[idx[k] * 4 + r], Et[r]);
        }
        f4 hv4;
#pragma unroll
        for (int r = 0; r < 4; ++r) {
            const float hv = s12[8 + r] + Et[r];
            hv4[r] = SCALEF * 0.5f * hv *
                     (1.f + erff(hv * 0.70710678118654752f));
        }
        hsh[wid][lane] = hv4;
    }
    asm volatile("s_waitcnt lgkmcnt(0)" ::: "memory");

    // ---- phase 2: 16 tokens x 16 KB rows; B_w from L2, 1KB-coalesced nt stores
    f4 hv[16];
#pragma unroll
    for (int t = 0; t < 16; ++t) hv[t] = hsh[wid][t];

    const f4* __restrict__ b4 = (const f4*)B_w;
#pragma unroll 2
    for (int j = 0; j < 16; ++j) {
        const int c = lane + 64 * j;                 // f4-chunk within row
        const f4 B0 = b4[4 * c + 0], B1 = b4[4 * c + 1],
                 B2 = b4[4 * c + 2], B3 = b4[4 * c + 3];
#pragma unroll
        for (int t = 0; t < 16; ++t) {
            const f4 hh = hv[t];
            f4 v;
            v[0] = B0[0] * hh[0] + B0[1] * hh[1] + B0[2] * hh[2] + B0[3] * hh[3];
            v[1] = B1[0] * hh[0] + B1[1] * hh[1] + B1[2] * hh[2] + B1[3] * hh[3];
            v[2] = B2[0] * hh[0] + B2[1] * hh[1] + B2[2] * hh[2] + B2[3] * hh[3];
            v[3] = B3[0] * hh[0] + B3[1] * hh[1] + B3[2] * hh[2] + B3[3] * hh[3];
            __builtin_nontemporal_store(
                v, (f4*)out + (size_t)(tok0 + t) * 1024 + c);
        }
    }
}

extern "C" void kernel_launch(void* const* d_in, const int* in_sizes, int n_in,
                              void* d_out, int out_size, void* d_ws, size_t ws_size,
                              hipStream_t stream) {
    const float* x        = (const float*)d_in[0];
    const float* A_w      = (const float*)d_in[1];
    const float* B_w      = (const float*)d_in[2];
    const float* router_w = (const float*)d_in[3];
    const float* ev       = (const float*)d_in[4];
    float* out            = (float*)d_out;
    unsigned short* wq    = (unsigned short*)d_ws;   // 128 KB prepacked B-frags

    k0_pack<<<32, 256, 0, stream>>>(A_w, router_w, wq);
    tmlora_main<<<256, 256, 0, stream>>>(x, wq, B_w, ev, out);
}

// Round 12
// 95.361 us; speedup vs baseline: 3.7744x; 1.1130x over previous
//
#include <hip/hip_runtime.h>
#include <cmath>

typedef float f4 __attribute__((ext_vector_type(4)));
typedef float f32x4 __attribute__((ext_vector_type(4)));
typedef short bf16x8 __attribute__((ext_vector_type(8)));
typedef unsigned short u16x8 __attribute__((ext_vector_type(8)));
typedef unsigned int u32x4 __attribute__((ext_vector_type(4)));

#define SCALEF 8.0f   // alpha/rank = 32/4

__device__ __forceinline__ unsigned cvtpk(float lo, float hi) {
    unsigned r;
    asm("v_cvt_pk_bf16_f32 %0, %1, %2" : "=v"(r) : "v"(lo), "v"(hi));
    return r;
}

// 8 consecutive-k f32 -> bf16x8 A-fragment (elem j = k j)
__device__ __forceinline__ bf16x8 packA(const f4 a, const f4 b) {
    u32x4 u;
    u[0] = cvtpk(a[0], a[1]);
    u[1] = cvtpk(a[2], a[3]);
    u[2] = cvtpk(b[0], b[1]);
    u[3] = cvtpk(b[2], b[3]);
    return __builtin_bit_cast(bf16x8, u);
}

// ---- k0: prepack 12 weight rows into MFMA B-fragment stream (bf16) -------
// entry idx = s*64 + l (s = k-step 0..127, l = lane): 8 bf16 =
// W[l&15][32s + (l>>4)*8 + j], zero-padded for w >= 12.  128 KB total.
__global__ __launch_bounds__(256, 4) void k0_pack(
    const float* __restrict__ A_w,
    const float* __restrict__ router_w,
    unsigned short* __restrict__ wq)
{
    const int idx = blockIdx.x * 256 + threadIdx.x;   // 0..8191
    const int l = idx & 63, s = idx >> 6;
    const int w = l & 15;
    const int kb = 32 * s + (l >> 4) * 8;
    u16x8 o = (u16x8)0;
    if (w < 12) {
        const float* __restrict__ row = (w < 8)
            ? router_w + (size_t)w * 4096
            : A_w + (size_t)(w - 8) * 4096;
#pragma unroll
        for (int j = 0; j < 8; ++j) {
            union { float f; unsigned u; } a;
            a.f = row[kb + j];
            o[j] = (unsigned short)((a.u + 0x7FFFu + ((a.u >> 16) & 1u)) >> 16);
        }
    }
    *((u16x8*)wq + idx) = o;
}

// ---- main: 1024 blocks x 4 waves; block = 16-token tile, K split 4-way ----
__global__ __launch_bounds__(256, 4) void tmlora_main(
    const float* __restrict__ x,
    const unsigned short* __restrict__ wq,
    const float* __restrict__ B_w,
    const float* __restrict__ expert_vectors,
    float* __restrict__ out)
{
    __shared__ float red[4][16][17];   // [wave][token][weight], pad 17
    __shared__ f4    hsh[16];          // h per token (SCALEF folded)

    const int tid  = threadIdx.x;
    const int wid  = tid >> 6, lane = tid & 63;
    const int tok0 = blockIdx.x * 16;
    const int s0   = wid * 32;          // this wave's K-step base (K=1024)

    // A: lane l covers row tok0+(l&15), k-chunk (l>>4)*8 within each step
    const f4* __restrict__ xr =
        (const f4*)x + ((size_t)(tok0 + (lane & 15)) << 10) + ((lane >> 4) << 1);
    const u16x8* __restrict__ wr = (const u16x8*)wq + lane;

    // ---- K-loop: 32 steps, two banks of 4, 8 steps of loads in flight ----
    f4 a0[4], a1[4], c0[4], c1[4];
    u16x8 wb[4], wc[4];
#pragma unroll
    for (int i = 0; i < 4; ++i) {
        a0[i] = xr[8 * (s0 + i)];
        a1[i] = xr[8 * (s0 + i) + 1];
        wb[i] = wr[(s0 + i) << 6];
    }
#pragma unroll
    for (int i = 0; i < 4; ++i) {
        c0[i] = xr[8 * (s0 + 4 + i)];
        c1[i] = xr[8 * (s0 + 4 + i) + 1];
        wc[i] = wr[(s0 + 4 + i) << 6];
    }

    f32x4 acc = {0.f, 0.f, 0.f, 0.f};

#pragma unroll 1
    for (int it = 0; it < 4; ++it) {
        const int sb = s0 + it * 8;
#pragma unroll
        for (int i = 0; i < 4; ++i)
            acc = __builtin_amdgcn_mfma_f32_16x16x32_bf16(
                packA(a0[i], a1[i]), __builtin_bit_cast(bf16x8, wb[i]), acc, 0, 0, 0);
        if (it < 3) {
#pragma unroll
            for (int i = 0; i < 4; ++i) {
                a0[i] = xr[8 * (sb + 8 + i)];
                a1[i] = xr[8 * (sb + 8 + i) + 1];
                wb[i] = wr[(sb + 8 + i) << 6];
            }
        }
#pragma unroll
        for (int i = 0; i < 4; ++i)
            acc = __builtin_amdgcn_mfma_f32_16x16x32_bf16(
                packA(c0[i], c1[i]), __builtin_bit_cast(bf16x8, wc[i]), acc, 0, 0, 0);
        if (it < 3) {
#pragma unroll
            for (int i = 0; i < 4; ++i) {
                c0[i] = xr[8 * (sb + 12 + i)];
                c1[i] = xr[8 * (sb + 12 + i) + 1];
                wc[i] = wr[(sb + 12 + i) << 6];
            }
        }
    }

    // ---- per-wave C -> LDS (transposed); then block reduce ----
    // lane holds scores[token=(lane>>4)*4+r][weight=lane&15]
#pragma unroll
    for (int r = 0; r < 4; ++r)
        red[wid][(lane >> 4) * 4 + r][lane & 15] = acc[r];
    __syncthreads();   // K-loop loads all consumed; drain is free

    // ---- epilogue: threads 0..15, one token each ----
    if (tid < 16) {
        float s12[12];
#pragma unroll
        for (int w = 0; w < 12; ++w)
            s12[w] = red[0][tid][w] + red[1][tid][w] +
                     red[2][tid][w] + red[3][tid][w];

        int   idx[4];
        float val[4];
#pragma unroll
        for (int k = 0; k < 4; ++k) {
            int bi = 0; float bv = s12[0];
#pragma unroll
            for (int e = 1; e < 8; ++e)
                if (s12[e] > bv) { bv = s12[e]; bi = e; }
            idx[k] = bi; val[k] = bv;
#pragma unroll
            for (int e = 0; e < 8; ++e)
                if (e == bi) s12[e] = -INFINITY;   // static-index knockout
        }
        float ex[4], se = 0.f;
#pragma unroll
        for (int k = 0; k < 4; ++k) { ex[k] = expf(val[k] - val[0]); se += ex[k]; }
        const float inv = 1.f / se;
        float Et[4] = {0.f, 0.f, 0.f, 0.f};
#pragma unroll
        for (int k = 0; k < 4; ++k) {
            const float wgt = ex[k] * inv;
#pragma unroll
            for (int r = 0; r < 4; ++r)
                Et[r] = fmaf(wgt, expert_vectors[idx[k] * 4 + r], Et[r]);
        }
        f4 hv4;
#pragma unroll
        for (int r = 0; r < 4; ++r) {
            const float hv = s12[8 + r] + Et[r];
            hv4[r] = SCALEF * 0.5f * hv *
                     (1.f + erff(hv * 0.70710678118654752f));
        }
        hsh[tid] = hv4;
    }
    __syncthreads();

    // ---- phase 2: block-wide stores; 16 tokens x 1024 f4 chunks ----
    f4 hv[16];
#pragma unroll
    for (int t = 0; t < 16; ++t) hv[t] = hsh[t];

    const f4* __restrict__ b4 = (const f4*)B_w;
#pragma unroll
    for (int j = 0; j < 4; ++j) {
        const int c = tid + 256 * j;                 // f4-chunk within row
        const f4 B0 = b4[4 * c + 0], B1 = b4[4 * c + 1],
                 B2 = b4[4 * c + 2], B3 = b4[4 * c + 3];
#pragma unroll
        for (int t = 0; t < 16; ++t) {
            const f4 hh = hv[t];
            f4 v;
            v[0] = B0[0] * hh[0] + B0[1] * hh[1] + B0[2] * hh[2] + B0[3] * hh[3];
            v[1] = B1[0] * hh[0] + B1[1] * hh[1] + B1[2] * hh[2] + B1[3] * hh[3];
            v[2] = B2[0] * hh[0] + B2[1] * hh[1] + B2[2] * hh[2] + B2[3] * hh[3];
            v[3] = B3[0] * hh[0] + B3[1] * hh[1] + B3[2] * hh[2] + B3[3] * hh[3];
            __builtin_nontemporal_store(
                v, (f4*)out + (size_t)(tok0 + t) * 1024 + c);
        }
    }
}

extern "C" void kernel_launch(void* const* d_in, const int* in_sizes, int n_in,
                              void* d_out, int out_size, void* d_ws, size_t ws_size,
                              hipStream_t stream) {
    const float* x        = (const float*)d_in[0];
    const float* A_w      = (const float*)d_in[1];
    const float* B_w      = (const float*)d_in[2];
    const float* router_w = (const float*)d_in[3];
    const float* ev       = (const float*)d_in[4];
    float* out            = (float*)d_out;
    unsigned short* wq    = (unsigned short*)d_ws;   // 128 KB prepacked B-frags

    k0_pack<<<32, 256, 0, stream>>>(A_w, router_w, wq);
    tmlora_main<<<1024, 256, 0, stream>>>(x, wq, B_w, ev, out);
}